// Round 1
// baseline (31587.323 us; speedup 1.0000x reference)
//
#include <hip/hip_runtime.h>
#include <hip/hip_bf16.h>

#define TSTEPS 4096
#define XD 256
#define HD 2048
#define YD 256
#define KD 2304   // XD + HD
#define NWG 256
#define NT 512

// ---- LDS layout (bytes) ----
#define WU_OFF 0
#define WR_OFF (8*KD*2)              // 36864
#define WC_OFF (16*KD*2)             // 73728
#define WY_OFF (24*KD*2)             // 110592
#define XB_OFF (WY_OFF + HD*4)       // 118784  x_t ping-pong: 2 x 256 floats
#define HBUF_OFF (XB_OFF + 2*XD*4)   // 120832  h_{t-1}: 2048 floats (tagged)
#define ZBUF_OFF (HBUF_OFF + HD*4)   // 129024  z = r*h: 2048 floats (tagged)
#define RED_OFF (ZBUF_OFF + HD*4)    // 137216  u[8], yp[8], bu[8], br[8], bc[8], by, hclean[8]
#define LDS_BYTES (RED_OFF + 256)    // 137472

// ---- workspace: ONLY exchange buffers. No flags, no go lines, no hub. ----
// Certification is embedded in the data: low 2 mantissa bits of every float
// carry epoch tag (t+1)&3. Ping-pong reuse is 2 epochs apart -> stale tag
// always differs by 2 mod 4. Memset zeroes tags to 0; first writes use 1/2.
#define HB0_OFF 0
#define HB1_OFF 8192
#define RB0_OFF 16384
#define RB1_OFF 24576
#define WS_ZERO_BYTES 32768

__device__ __forceinline__ float bflo(unsigned u){ return __uint_as_float(u << 16); }
__device__ __forceinline__ float bfhi(unsigned u){ return __uint_as_float(u & 0xffff0000u); }
__device__ __forceinline__ unsigned short f2bf(float f){
  unsigned b = __float_as_uint(f);
  b += 0x7fffu + ((b >> 16) & 1u);   // RTNE (inputs finite)
  return (unsigned short)(b >> 16);
}
__device__ __forceinline__ float sigmoidf_(float x){ return 1.0f / (1.0f + __expf(-x)); }

// Tagged publish: dword store is atomic (no tearing); tag in low 2 mantissa
// bits self-certifies visibility. Agent scope -> reaches LLC (cross-XCD).
__device__ __forceinline__ void storetag(float* p, float v, unsigned tag){
  unsigned b = (__float_as_uint(v) & ~3u) | tag;
  __hip_atomic_store((unsigned*)p, b, __ATOMIC_RELAXED, __HIP_MEMORY_SCOPE_AGENT);
}

// Single-round-trip certified consume: poll the 16B data chunk itself until
// all 4 dwords carry the expected epoch tag. Replaces the entire relay
// barrier (flag store -> hub poll -> go store -> go poll -> data load).
__device__ __forceinline__ float4 pollchunk16(const float4* p, unsigned tag, long* budget){
  float4 r;
  for (;;) {
    asm volatile("global_load_dwordx4 %0, %1, off sc1\n\t"
                 "s_waitcnt vmcnt(0)"
                 : "=v"(r) : "v"(p) : "memory");
    unsigned m = (__float_as_uint(r.x) ^ tag) | (__float_as_uint(r.y) ^ tag)
               | (__float_as_uint(r.z) ^ tag) | (__float_as_uint(r.w) ^ tag);
    if ((m & 3u) == 0u) break;
    if (--(*budget) < 0) break;      // anti-hang: proceed rather than deadlock
    __builtin_amdgcn_s_sleep(1);
  }
  return r;
}

// Unrolled K-chunk of a column dot: v[4*(lane+STRIDE*i)] dot bf16 weights.
template<int I0, int I1, int STRIDE>
__device__ __forceinline__ void dotacc(const float* v, const unsigned short* wcol,
                                       int lane, float4& acc){
  #pragma unroll
  for (int i = I0; i < I1; ++i) {
    int k = 4 * (lane + STRIDE * i);
    float4 vv = *(const float4*)(v + k);
    uint2  wq = *(const uint2*)(wcol + k);
    acc.x = fmaf(vv.x, bflo(wq.x), acc.x);
    acc.y = fmaf(vv.y, bfhi(wq.x), acc.y);
    acc.z = fmaf(vv.z, bflo(wq.y), acc.z);
    acc.w = fmaf(vv.w, bfhi(wq.y), acc.w);
  }
}

extern "C" __global__ void __launch_bounds__(NT)
gru_persistent(const float* __restrict__ x,  const float* __restrict__ h0,
               const float* __restrict__ Wc, const float* __restrict__ Wu,
               const float* __restrict__ Wr, const float* __restrict__ bc,
               const float* __restrict__ bu, const float* __restrict__ br,
               const float* __restrict__ Wy, const float* __restrict__ by,
               float* __restrict__ out, unsigned* wsu)
{
  extern __shared__ char smem[];
  unsigned short* wuS = (unsigned short*)(smem + WU_OFF);
  unsigned short* wrS = (unsigned short*)(smem + WR_OFF);
  unsigned short* wcS = (unsigned short*)(smem + WC_OFF);
  float* wyS   = (float*)(smem + WY_OFF);
  float* xb    = (float*)(smem + XB_OFF);
  float* hbufS = (float*)(smem + HBUF_OFF);
  float* zbufS = (float*)(smem + ZBUF_OFF);
  float* red   = (float*)(smem + RED_OFF);

  float* hb[2] = { (float*)((char*)wsu + HB0_OFF), (float*)((char*)wsu + HB1_OFF) };
  float* rb[2] = { (float*)((char*)wsu + RB0_OFF), (float*)((char*)wsu + RB1_OFF) };

  const int wg = blockIdx.x, tid = threadIdx.x;
  const int col0 = 8 * wg;

  // ---- one-time weight staging: WG j owns gate cols [8j,8j+8), y col j ----
  for (int idx = tid; idx < 8*KD; idx += NT) {
    int c = idx & 7, k = idx >> 3;
    size_t g = (size_t)k * HD + col0 + c;   // W is [KD, 2048] row-major
    wuS[c*KD + k] = f2bf(Wu[g]);
    wrS[c*KD + k] = f2bf(Wr[g]);
    wcS[c*KD + k] = f2bf(Wc[g]);
  }
  for (int k = tid; k < HD; k += NT) wyS[k] = Wy[(size_t)k * YD + wg];
  if (tid < 8) {
    red[16+tid] = bu[col0+tid];
    red[24+tid] = br[col0+tid];
    red[32+tid] = bc[col0+tid];
    red[56+tid] = h0[col0+tid];     // clean fp32 carry of own h slice
  }
  if (tid == 0) red[40] = by[wg];
  __syncthreads();

  long budget = 20000000;   // spin cap, then bail (no hang)

  // x prefetch pipeline: xpref holds x_t at the top of each step.
  float4 xpref = make_float4(0.f, 0.f, 0.f, 0.f);
  if (tid < XD/4) xpref = ((const float4*)x)[tid];

  const int hw = tid >> 5, l = tid & 31, c = hw & 7;   // phase-1 mapping
  const int w  = tid >> 6, l6 = tid & 63;              // phase-2 / y mapping
  const unsigned short* wcol = ((hw < 8) ? wuS : wrS) + c * KD;
  const unsigned short* ccol = wcS + w * KD;

  for (int t = 0; t < TSTEPS; ++t) {
    float* xcur = xb + (t & 1) * XD;          // ping-pong: no end-of-loop sync
    if (tid < XD/4) ((float4*)xcur)[tid] = xpref;

    // ---- h_{t-1} consume: poll tagged data directly (1 LLC round trip) ----
    if (t == 0) {
      ((float4*)hbufS)[tid] = ((const float4*)h0)[tid];
    } else {
      float4 hv = pollchunk16((const float4*)hb[(t+1)&1] + tid,
                              (unsigned)(t & 3), &budget);
      ((float4*)hbufS)[tid] = hv;
    }
    __syncthreads();                          // S1: x + h visible in LDS

    // ---- phase 1: Lu (half-waves 0-7), Lr (8-15), full K ----
    float4 a1 = make_float4(0.f, 0.f, 0.f, 0.f);
    dotacc<0, 2, 32>(xcur, wcol, l, a1);           // x part  (K 0..255)
    dotacc<0, 16, 32>(hbufS, wcol + XD, l, a1);    // h part  (K 256..2303)
    {
      float s = (a1.x + a1.y) + (a1.z + a1.w);
      s += __shfl_xor(s, 16); s += __shfl_xor(s, 8); s += __shfl_xor(s, 4);
      s += __shfl_xor(s, 2);  s += __shfl_xor(s, 1);
      if (l == 0) {
        if (hw < 8) red[c] = sigmoidf_(s + red[16+c]);               // u gate
        else storetag(rb[t&1] + col0 + c,
                      sigmoidf_(s + red[24+c]) * red[56+c],          // z = r*h (clean carry)
                      (unsigned)((t+1) & 3));
      }
    }

    // hidden window (covers z store flight): y[t-1] partials + x_{t+1} prefetch
    {
      int k = 256 * w + 4 * l6;
      float4 hv  = *(const float4*)(hbufS + k);
      float4 wy4 = *(const float4*)(wyS + k);
      float ys = fmaf(hv.x, wy4.x, fmaf(hv.y, wy4.y, fmaf(hv.z, wy4.z, hv.w * wy4.w)));
      ys += __shfl_xor(ys, 32); ys += __shfl_xor(ys, 16); ys += __shfl_xor(ys, 8);
      ys += __shfl_xor(ys, 4);  ys += __shfl_xor(ys, 2);  ys += __shfl_xor(ys, 1);
      if (l6 == 0) red[8 + w] = ys;
    }
    if (tid < XD/4 && t + 1 < TSTEPS)
      xpref = ((const float4*)(x + (size_t)(t+1) * XD))[tid];

    // ---- z consume: poll tagged data directly ----
    {
      float4 rv = pollchunk16((const float4*)rb[t&1] + tid,
                              (unsigned)((t+1) & 3), &budget);
      ((float4*)zbufS)[tid] = rv;
    }
    __syncthreads();                          // S2: z + u + y-partials visible

    // y[t-1] store: fire-and-forget, latency hidden under phase 2
    if (tid == 0 && t > 0) {
      float y = red[8]+red[9]+red[10]+red[11]+red[12]+red[13]+red[14]+red[15] + red[40];
      out[(size_t)(t-1) * YD + wg] = y;
    }

    // ---- phase 2: candidate (wave w -> col w), full K ----
    {
      float4 a2 = make_float4(0.f, 0.f, 0.f, 0.f);
      dotacc<0, 1, 64>(xcur, ccol, l6, a2);          // x part
      dotacc<0, 8, 64>(zbufS, ccol + XD, l6, a2);    // z part
      float s = (a2.x + a2.y) + (a2.z + a2.w);
      s += __shfl_xor(s, 32); s += __shfl_xor(s, 16); s += __shfl_xor(s, 8);
      s += __shfl_xor(s, 4);  s += __shfl_xor(s, 2);  s += __shfl_xor(s, 1);
      if (l6 == 0) {
        float cc = tanhf(s + red[32 + w]);
        float u  = red[w];
        float hp = red[56 + w];                      // clean fp32 carry
        float hn = cc * u + hp * (1.0f - u);
        red[56 + w] = hn;                            // keep recurrence clean
        storetag(hb[t&1] + col0 + w, hn, (unsigned)((t+1) & 3));
      }
    }
    // no end-of-loop barrier: S1-next orders phase-2 reads vs next writes
  }

  // ---- epilogue: y[T-1] and h_fin ----
  {
    float4 hv = pollchunk16((const float4*)hb[(TSTEPS-1)&1] + tid,
                            (unsigned)(TSTEPS & 3), &budget);
    ((float4*)hbufS)[tid] = hv;
  }
  __syncthreads();
  {
    int k = 256 * w + 4 * l6;
    float4 hv  = *(const float4*)(hbufS + k);
    float4 wy4 = *(const float4*)(wyS + k);
    float ys = fmaf(hv.x, wy4.x, fmaf(hv.y, wy4.y, fmaf(hv.z, wy4.z, hv.w * wy4.w)));
    ys += __shfl_xor(ys, 32); ys += __shfl_xor(ys, 16); ys += __shfl_xor(ys, 8);
    ys += __shfl_xor(ys, 4);  ys += __shfl_xor(ys, 2);  ys += __shfl_xor(ys, 1);
    if (l6 == 0) red[8 + w] = ys;
  }
  __syncthreads();
  if (tid == 0) {
    float y = red[8]+red[9]+red[10]+red[11]+red[12]+red[13]+red[14]+red[15] + red[40];
    out[(size_t)(TSTEPS-1) * YD + wg] = y;
  }
  if (tid < 8) out[(size_t)TSTEPS * YD + col0 + tid] = red[56 + tid];  // clean h_fin
}

extern "C" void kernel_launch(void* const* d_in, const int* in_sizes, int n_in,
                              void* d_out, int out_size, void* d_ws, size_t ws_size,
                              hipStream_t stream) {
  const float* x  = (const float*)d_in[0];
  const float* h0 = (const float*)d_in[1];
  const float* Wc = (const float*)d_in[2];
  const float* Wu = (const float*)d_in[3];
  const float* Wr = (const float*)d_in[4];
  const float* bc = (const float*)d_in[5];
  const float* bu = (const float*)d_in[6];
  const float* br = (const float*)d_in[7];
  const float* Wy = (const float*)d_in[8];
  const float* by = (const float*)d_in[9];
  float* out = (float*)d_out;
  unsigned* wsu = (unsigned*)d_ws;

  // >64 KB dynamic LDS on gfx950 (160 KB/CU). Idempotent; capture-safe.
  hipFuncSetAttribute((const void*)gru_persistent,
                      hipFuncAttributeMaxDynamicSharedMemorySize, LDS_BYTES);
  hipMemsetAsync(d_ws, 0, WS_ZERO_BYTES, stream);   // tag bits -> 0 (first epochs use 1/2)
  gru_persistent<<<dim3(NWG), dim3(NT), LDS_BYTES, stream>>>(
      x, h0, Wc, Wu, Wr, bc, bu, br, Wy, by, out, wsu);
}

// Round 2
// 21171.510 us; speedup vs baseline: 1.4920x; 1.4920x over previous
//
#include <hip/hip_runtime.h>
#include <hip/hip_bf16.h>

#define TSTEPS 4096
#define XD 256
#define HD 2048
#define YD 256
#define KD 2304   // XD + HD
#define NWG 256
#define NT 512

// ---- LDS layout (bytes) ----
#define WU_OFF 0
#define WR_OFF (8*KD*2)              // 36864
#define WC_OFF (16*KD*2)             // 73728
#define WY_OFF (24*KD*2)             // 110592
#define HBUF_OFF (WY_OFF + HD*4)     // 118784  h_{t-1} (2048 f)
#define ZBUF_OFF (HBUF_OFF + HD*4)   // 126976  z = r*h  (2048 f)
#define RED_OFF (ZBUF_OFF + HD*4)    // 135168  yp[8..15], bu[16..23], br[24..31], bc[32..39], by[40]
#define LDS_BYTES (RED_OFF + 256)    // 135424

// ---- workspace (u32 indices; flag/go lines 128B apart) ----
// Monotone epoch flags. R2-relay restored (R1 lesson: data-polling without
// the hub = read storm in the produce window -> producers' stores delayed).
#define HFLAGS_U32 0                 // hflags[wg] at wg*32   (256 lines, 32 KB)
#define RFLAGS_U32 8192              // rflags[wg]            (32 KB)
#define HGO_U32    16384             // 64 lines (8 KB): per (wg&7, wave)
#define RGO_U32    18432             // 64 lines (8 KB)
#define WS_ZERO_BYTES 81920
#define HB0_OFF 81920                // h exchange buffers (8 KB each)
#define HB1_OFF 90112
#define RB0_OFF 98304                // z exchange buffers
#define RB1_OFF 106496

__device__ __forceinline__ float bflo(unsigned u){ return __uint_as_float(u << 16); }
__device__ __forceinline__ float bfhi(unsigned u){ return __uint_as_float(u & 0xffff0000u); }
__device__ __forceinline__ unsigned short f2bf(float f){
  unsigned b = __float_as_uint(f);
  b += 0x7fffu + ((b >> 16) & 1u);   // RTNE (inputs finite)
  return (unsigned short)(b >> 16);
}
__device__ __forceinline__ float sigmoidf_(float x){ return 1.0f / (1.0f + __expf(-x)); }

__device__ __forceinline__ void gst32f(float* p, float v){
  __hip_atomic_store(p, v, __ATOMIC_RELAXED, __HIP_MEMORY_SCOPE_AGENT);
}
__device__ __forceinline__ void flagst(unsigned* p, unsigned v){
  __hip_atomic_store(p, v, __ATOMIC_RELAXED, __HIP_MEMORY_SCOPE_AGENT);
}
__device__ __forceinline__ void spinflag(const unsigned* p, unsigned epoch, long* budget){
  while (__hip_atomic_load(p, __ATOMIC_RELAXED, __HIP_MEMORY_SCOPE_AGENT) < epoch) {
    if (--(*budget) < 0) break;     // anti-hang: proceed rather than deadlock
    __builtin_amdgcn_s_sleep(1);
  }
}

// AGENT-scope coalesced 16B load (sc1 = LLC-serviced). Issued ONLY after
// relay certification — no speculative read storms.
__device__ __forceinline__ float4 cohload16(const float4* p){
  float4 r;
  asm volatile("global_load_dwordx4 %0, %1, off sc1\n\t"
               "s_waitcnt vmcnt(0)"
               : "=v"(r) : "v"(p) : "memory");
  return r;
}
// Non-blocking issue (WG0 hides its data RTT under the hidden-window work).
__device__ __forceinline__ float4 cohload16_issue(const float4* p){
  float4 r;
  asm volatile("global_load_dwordx4 %0, %1, off sc1"
               : "=v"(r) : "v"(p) : "memory");
  return r;
}

// Hub side (WG0): 255 threads poll 255 distinct flag lines; then 64 go
// lines (one per (wg&7, wave)) broadcast the epoch. WG0 polls FIRST (no
// window before) so the go broadcast isn't delayed by WG0's local work.
__device__ __forceinline__ void hub_wait(unsigned* flags, unsigned* go,
                                         unsigned epoch, int tid, long* budget){
  if (tid >= 1 && tid < NWG) spinflag(flags + tid*32, epoch, budget);
  __syncthreads();
  if (tid < 64) flagst(go + tid*32, epoch);
}
// Consumer side: lane 0 of each wave spins on its own go line (32 pollers
// per line), then the wave proceeds — no workgroup barrier needed here.
__device__ __forceinline__ void wave_wait(unsigned* go, unsigned epoch,
                                          int line, int l6, long* budget){
  if (l6 == 0) spinflag(go + line*32, epoch, budget);
}

// Unrolled K-chunk of a column dot: v[4*(l6+64*i)] dot bf16 weights.
template<int I0, int I1, int STRIDE>
__device__ __forceinline__ void dotacc(const float* v, const unsigned short* wcol,
                                       int lane, float4& acc){
  #pragma unroll
  for (int i = I0; i < I1; ++i) {
    int k = 4 * (lane + STRIDE * i);
    float4 vv = *(const float4*)(v + k);
    uint2  wq = *(const uint2*)(wcol + k);
    acc.x = fmaf(vv.x, bflo(wq.x), acc.x);
    acc.y = fmaf(vv.y, bfhi(wq.x), acc.y);
    acc.z = fmaf(vv.z, bflo(wq.y), acc.z);
    acc.w = fmaf(vv.w, bfhi(wq.y), acc.w);
  }
}

// x-part from registers: all three gates use the same K-mapping, so each
// thread holds its own x float4 (no LDS staging, no barrier for x).
__device__ __forceinline__ void xpart(const float4 xq, const unsigned short* wcol,
                                      int l6, float4& acc){
  uint2 wq = *(const uint2*)(wcol + 4*l6);
  acc.x = fmaf(xq.x, bflo(wq.x), acc.x);
  acc.y = fmaf(xq.y, bfhi(wq.x), acc.y);
  acc.z = fmaf(xq.z, bflo(wq.y), acc.z);
  acc.w = fmaf(xq.w, bfhi(wq.y), acc.w);
}

__device__ __forceinline__ float redux64(float4 a){
  float s = (a.x + a.y) + (a.z + a.w);
  s += __shfl_xor(s, 32); s += __shfl_xor(s, 16); s += __shfl_xor(s, 8);
  s += __shfl_xor(s, 4);  s += __shfl_xor(s, 2);  s += __shfl_xor(s, 1);
  return s;
}

extern "C" __global__ void __launch_bounds__(NT)
gru_persistent(const float* __restrict__ x,  const float* __restrict__ h0,
               const float* __restrict__ Wc, const float* __restrict__ Wu,
               const float* __restrict__ Wr, const float* __restrict__ bc,
               const float* __restrict__ bu, const float* __restrict__ br,
               const float* __restrict__ Wy, const float* __restrict__ by,
               float* __restrict__ out, unsigned* wsu)
{
  extern __shared__ char smem[];
  unsigned short* wuS = (unsigned short*)(smem + WU_OFF);
  unsigned short* wrS = (unsigned short*)(smem + WR_OFF);
  unsigned short* wcS = (unsigned short*)(smem + WC_OFF);
  float* wyS   = (float*)(smem + WY_OFF);
  float* hbufS = (float*)(smem + HBUF_OFF);
  float* zbufS = (float*)(smem + ZBUF_OFF);
  float* red   = (float*)(smem + RED_OFF);

  unsigned* hflags = wsu + HFLAGS_U32;
  unsigned* rflags = wsu + RFLAGS_U32;
  unsigned* hgo    = wsu + HGO_U32;
  unsigned* rgo    = wsu + RGO_U32;
  float* hb[2] = { (float*)((char*)wsu + HB0_OFF), (float*)((char*)wsu + HB1_OFF) };
  float* rb[2] = { (float*)((char*)wsu + RB0_OFF), (float*)((char*)wsu + RB1_OFF) };

  const int wg = blockIdx.x, tid = threadIdx.x;
  const int col0 = 8 * wg;

  // ---- one-time weight staging: WG j owns gate cols [8j,8j+8), y col j ----
  for (int idx = tid; idx < 8*KD; idx += NT) {
    int c = idx & 7, k = idx >> 3;
    size_t g = (size_t)k * HD + col0 + c;   // W is [KD, 2048] row-major
    wuS[c*KD + k] = f2bf(Wu[g]);
    wrS[c*KD + k] = f2bf(Wr[g]);
    wcS[c*KD + k] = f2bf(Wc[g]);
  }
  for (int k = tid; k < HD; k += NT) wyS[k] = Wy[(size_t)k * YD + wg];
  if (tid < 8) {
    red[16+tid] = bu[col0+tid];
    red[24+tid] = br[col0+tid];
    red[32+tid] = bc[col0+tid];
  }
  if (tid == 0) red[40] = by[wg];
  __syncthreads();

  long budget = 20000000;   // spin cap, then bail (no hang)

  const int w  = tid >> 6, l6 = tid & 63;          // wave / lane
  const int goline = ((wg & 7) << 3) + w;          // per-wave go line
  const unsigned short* ucol = wuS + w * KD;
  const unsigned short* rcol = wrS + w * KD;
  const unsigned short* ccol = wcS + w * KD;

  // per-thread x chunk (same floats for every wave; L2-broadcast)
  float4 xq = ((const float4*)x)[l6];
  float ureg = 0.f;

  // hidden-window work: u gate (off critical path), y[t-1] partials,
  // x_{t+1} prefetch. Runs under the z-relay latency.
  auto window = [&](int t){
    float4 au = make_float4(0.f, 0.f, 0.f, 0.f);
    xpart(xq, ucol, l6, au);
    dotacc<1, 9, 64>(hbufS - XD, ucol, l6, au);
    ureg = sigmoidf_(redux64(au) + red[16 + w]);
    int k = 256 * w + 4 * l6;
    float4 hv4 = *(const float4*)(hbufS + k);
    float4 wy4 = *(const float4*)(wyS + k);
    float ys = fmaf(hv4.x, wy4.x, fmaf(hv4.y, wy4.y, fmaf(hv4.z, wy4.z, hv4.w * wy4.w)));
    ys += __shfl_xor(ys, 32); ys += __shfl_xor(ys, 16); ys += __shfl_xor(ys, 8);
    ys += __shfl_xor(ys, 4);  ys += __shfl_xor(ys, 2);  ys += __shfl_xor(ys, 1);
    if (l6 == 0) red[8 + w] = ys;
    if (t + 1 < TSTEPS) xq = ((const float4*)(x + (size_t)(t+1) * XD))[l6];
  };

  for (int t = 0; t < TSTEPS; ++t) {
    // r x-part (register FMAs) — overlaps the h relay legs
    float4 a1 = make_float4(0.f, 0.f, 0.f, 0.f);
    xpart(xq, rcol, l6, a1);

    // ---- h_{t-1} exchange ----
    if (t == 0) {
      ((float4*)hbufS)[tid] = ((const float4*)h0)[tid];
    } else {
      if (wg == 0) hub_wait(hflags, hgo, (unsigned)t, tid, &budget);
      else         wave_wait(hgo, (unsigned)t, goline, l6, &budget);
      float4 hv = cohload16((const float4*)hb[(t+1)&1] + tid);  // certified
      ((float4*)hbufS)[tid] = hv;
    }
    __syncthreads();                                 // S1: h visible in LDS

    // ---- critical r-dot: wave w -> col col0+w, h part only ----
    dotacc<1, 9, 64>(hbufS - XD, rcol, l6, a1);
    {
      float s = redux64(a1);
      if (l6 == 0)
        gst32f(rb[t&1] + col0 + w,
               sigmoidf_(s + red[24 + w]) * hbufS[col0 + w]);   // z = r*h
    }
    __syncthreads();                                 // drain z stores (vmcnt 0)
    if (tid == 0) flagst(rflags + wg*32, (unsigned)(t+1));

    // c x-part with x_t BEFORE window's prefetch overwrites xq
    float4 a2 = make_float4(0.f, 0.f, 0.f, 0.f);
    xpart(xq, ccol, l6, a2);

    // ---- z exchange (window overlaps the wait / WG0's data RTT) ----
    float4 rv;
    if (wg != 0) {
      window(t);
      wave_wait(rgo, (unsigned)(t+1), goline, l6, &budget);
      rv = cohload16((const float4*)rb[t&1] + tid);             // certified
    } else {
      hub_wait(rflags, rgo, (unsigned)(t+1), tid, &budget);
      rv = cohload16_issue((const float4*)rb[t&1] + tid);       // issue early
      window(t);                                                // hide RTT
      asm volatile("s_waitcnt vmcnt(0)" ::: "memory");
    }
    ((float4*)zbufS)[tid] = rv;
    __syncthreads();                                 // S2: z + y-partials visible

    // y[t-1] store: fire-and-forget, latency hidden under phase 2
    if (tid == 0 && t > 0) {
      float y = red[8]+red[9]+red[10]+red[11]+red[12]+red[13]+red[14]+red[15] + red[40];
      out[(size_t)(t-1) * YD + wg] = y;
    }

    // ---- phase 2: candidate (wave w -> col col0+w), z part ----
    dotacc<1, 9, 64>(zbufS - XD, ccol, l6, a2);
    {
      float s = redux64(a2);
      if (l6 == 0) {
        float cc = tanhf(s + red[32 + w]);
        float hp = hbufS[col0 + w];
        gst32f(hb[t&1] + col0 + w, cc * ureg + hp * (1.0f - ureg));  // h_t slice
      }
    }
    __syncthreads();                                 // drain h stores
    if (tid == 0) flagst(hflags + wg*32, (unsigned)(t+1));
  }

  // ---- epilogue: y[T-1] and h_fin ----
  if (wg == 0) hub_wait(hflags, hgo, (unsigned)TSTEPS, tid, &budget);
  else         wave_wait(hgo, (unsigned)TSTEPS, goline, l6, &budget);
  {
    float4 hv = cohload16((const float4*)hb[(TSTEPS-1)&1] + tid);
    ((float4*)hbufS)[tid] = hv;
  }
  __syncthreads();
  {
    int k = 256 * w + 4 * l6;
    float4 hv4 = *(const float4*)(hbufS + k);
    float4 wy4 = *(const float4*)(wyS + k);
    float ys = fmaf(hv4.x, wy4.x, fmaf(hv4.y, wy4.y, fmaf(hv4.z, wy4.z, hv4.w * wy4.w)));
    ys += __shfl_xor(ys, 32); ys += __shfl_xor(ys, 16); ys += __shfl_xor(ys, 8);
    ys += __shfl_xor(ys, 4);  ys += __shfl_xor(ys, 2);  ys += __shfl_xor(ys, 1);
    if (l6 == 0) red[8 + w] = ys;
  }
  __syncthreads();
  if (tid == 0) {
    float y = red[8]+red[9]+red[10]+red[11]+red[12]+red[13]+red[14]+red[15] + red[40];
    out[(size_t)(TSTEPS-1) * YD + wg] = y;
  }
  if (tid < 8) out[(size_t)TSTEPS * YD + col0 + tid] = hbufS[col0 + tid];
}

extern "C" void kernel_launch(void* const* d_in, const int* in_sizes, int n_in,
                              void* d_out, int out_size, void* d_ws, size_t ws_size,
                              hipStream_t stream) {
  const float* x  = (const float*)d_in[0];
  const float* h0 = (const float*)d_in[1];
  const float* Wc = (const float*)d_in[2];
  const float* Wu = (const float*)d_in[3];
  const float* Wr = (const float*)d_in[4];
  const float* bc = (const float*)d_in[5];
  const float* bu = (const float*)d_in[6];
  const float* br = (const float*)d_in[7];
  const float* Wy = (const float*)d_in[8];
  const float* by = (const float*)d_in[9];
  float* out = (float*)d_out;
  unsigned* wsu = (unsigned*)d_ws;

  // >64 KB dynamic LDS on gfx950 (160 KB/CU). Idempotent; capture-safe.
  hipFuncSetAttribute((const void*)gru_persistent,
                      hipFuncAttributeMaxDynamicSharedMemorySize, LDS_BYTES);
  hipMemsetAsync(d_ws, 0, WS_ZERO_BYTES, stream);   // zero all flag/go epochs
  gru_persistent<<<dim3(NWG), dim3(NT), LDS_BYTES, stream>>>(
      x, h0, Wc, Wu, Wr, bc, bu, br, Wy, by, out, wsu);
}